// Round 5
// baseline (938.881 us; speedup 1.0000x reference)
//
#include <hip/hip_runtime.h>
#include <hip/hip_fp16.h>
#include <math.h>
#include <stdint.h>

// Geometry constants
#define VIEWS 512
#define NDET 736
#define NX 256
#define NY 256
#define EXTENT 2
#define SINO_LEN (VIEWS * NDET)          // 376832
#define NVOX (NX * NY)                   // 65536
#define PER_VOX (VIEWS * EXTENT)         // 1024

// fp16 x segmentation: 6 passes x 128KB LDS segments
#define SEGB 131072                      // bytes of fp16 x staged per pass
#define NPASS 6                          // ceil(753664 / 131072)
#define XWS_BYTES (NPASS * SEGB)         // 786432
#define XWS_HALVES (XWS_BYTES / 2)       // 393216 (zero-padded past 376832)

// SCALE = (2*pi - 0) / (2 * VIEWS * EXTENT) = pi / 1024
__device__ __constant__ float kScale = (float)(M_PI / 1024.0);

typedef int   v4i __attribute__((ext_vector_type(4)));
typedef float v4f __attribute__((ext_vector_type(4)));

// ---------------------------------------------------------------------------
// Kernel A: convert x (f32, 376832) -> fp16 in d_ws, zero-padded to 393216
// halves so staging can read full 6*128KB segments.
// ---------------------------------------------------------------------------
__global__ __launch_bounds__(256) void convert_x_kernel(
    const float* __restrict__ x, ushort* __restrict__ xh)
{
    const int t = blockIdx.x * 256 + threadIdx.x;   // 0..98303
    const int e = t * 4;
    ushort4 u;
    if (e < SINO_LEN) {                  // SINO_LEN % 4 == 0, so full quads
        const float4 v = *(const float4*)(x + e);
        u.x = __half_as_ushort(__float2half(v.x));
        u.y = __half_as_ushort(__float2half(v.y));
        u.z = __half_as_ushort(__float2half(v.z));
        u.w = __half_as_ushort(__float2half(v.w));
    } else {
        u.x = u.y = u.z = u.w = 0;
    }
    *(ushort4*)(xh + e) = u;
}

// ---------------------------------------------------------------------------
// Kernel B: segmented-LDS backprojection, round 5.
//
// r4 evidence: probe work (6 VALU + 1 ds_read per pair per pass) is the
// bottleneck (VALUBusy 62%); total probes = 67.1M * NPASS.
// Changes vs r4:
//   1. NPASS 12 -> 6 (128KB segments): probes halve.
//   2. Packed pair encoding (seg<<20 | byteoff&0x1FFFF): probe = sub, cmp,
//      and, cndmask, cvt, fma. No separate per-pass address computation.
//   3. T14 async staging: 128KB LDS -> 1 block/CU, so staging stalls have
//      no sibling block to hide them. Reg-stage xh (32 VGPR/thread): issue
//      global loads for seg p+1 before probing seg p; ds_write after the
//      barrier. Latency hides under the probe phase.
// Geometry: 2048 blocks x 1024 threads; 32 voxels/block; 32 threads/voxel;
// 32 pairs/thread; 16 waves/CU (50% occ).
// ---------------------------------------------------------------------------
__global__ __launch_bounds__(1024, 4) void backproj_lds2_kernel(
    const ushort* __restrict__ xh,    // [XWS_HALVES] fp16 x, zero-padded
    const float*  __restrict__ weight,// [NVOX * PER_VOX]
    const float*  __restrict__ bias,  // [NVOX]
    const int*    __restrict__ indices,// [NVOX * PER_VOX]
    float*        __restrict__ out)   // [NVOX]
{
    extern __shared__ unsigned char xs[];  // SEGB bytes

    const int tid = threadIdx.x;        // 0..1023
    const int vv  = tid >> 5;           // voxel-in-block 0..31
    const int q   = tid & 31;           // thread-in-voxel 0..31

    const int    vox0  = blockIdx.x * 32;
    const size_t pbase = (size_t)(vox0 + vv) * PER_VOX;

    const v4i* ip = (const v4i*)(indices + pbase);
    const v4f* wp = (const v4f*)(weight + pbase);

    // My 32 pairs (8 int4 + 8 float4), coalesced, non-temporal (must not
    // evict xh from L2).
    v4i pk[8];
    v4f w4[8];
#pragma unroll
    for (int k = 0; k < 8; ++k) pk[k] = __builtin_nontemporal_load(&ip[q + k * 32]);
#pragma unroll
    for (int k = 0; k < 8; ++k) w4[k] = __builtin_nontemporal_load(&wp[q + k * 32]);

    // Pack each index: byteoff = idx*2 (20 bits used);
    // packed = (seg << 20) | (byteoff & 0x1FFFF), seg = byteoff >> 17.
#pragma unroll
    for (int k = 0; k < 8; ++k) {
        int b;
        b = pk[k].x << 1; pk[k].x = ((b >> 17) << 20) | (b & (SEGB - 1));
        b = pk[k].y << 1; pk[k].y = ((b >> 17) << 20) | (b & (SEGB - 1));
        b = pk[k].z << 1; pk[k].z = ((b >> 17) << 20) | (b & (SEGB - 1));
        b = pk[k].w << 1; pk[k].w = ((b >> 17) << 20) | (b & (SEGB - 1));
    }

    // --- T14 staging machinery -------------------------------------------
    // Identity layout: LDS byte o  <=>  xh byte (seg*SEGB + o).
    // Per thread: 8 x float4 = 128B. Lane-contiguous 16B chunks -> both the
    // global loads and the ds_writes are coalesced/conflict-benign.
    float4 r[8];
    const unsigned soff = (unsigned)tid * 16;

#define ISSUE(SEG)                                                          \
    {                                                                       \
        const unsigned char* gp = (const unsigned char*)xh +                \
                                  (size_t)(SEG) * SEGB;                     \
        _Pragma("unroll")                                                   \
        for (int k = 0; k < 8; ++k)                                         \
            r[k] = *(const float4*)(gp + (unsigned)(k * 16384) + soff);     \
    }
#define COMMIT()                                                            \
    {                                                                       \
        _Pragma("unroll")                                                   \
        for (int k = 0; k < 8; ++k)                                         \
            *(float4*)(xs + (unsigned)(k * 16384) + soff) = r[k];           \
    }

    // Prologue: stage seg 0, start seg 1 loads.
    ISSUE(0);
    COMMIT();          // compiler inserts the per-reg vmcnt waits
    ISSUE(1);
    __syncthreads();   // seg 0 visible

    float a0 = 0.0f, a1 = 0.0f, a2 = 0.0f, a3 = 0.0f;

#pragma unroll
    for (int p = 0; p < NPASS; ++p) {
        const unsigned pb = (unsigned)p << 20;

        // Probe my 32 pairs against resident segment p.
#pragma unroll
        for (int k = 0; k < 8; ++k) {
            {
                const unsigned t = (unsigned)pk[k].x - pb;
                const unsigned a = t & (SEGB - 1);
                const float   ws = (t < (unsigned)SEGB) ? w4[k].x : 0.0f;
                a0 = fmaf(__half2float(*(const __half*)(xs + a)), ws, a0);
            }
            {
                const unsigned t = (unsigned)pk[k].y - pb;
                const unsigned a = t & (SEGB - 1);
                const float   ws = (t < (unsigned)SEGB) ? w4[k].y : 0.0f;
                a1 = fmaf(__half2float(*(const __half*)(xs + a)), ws, a1);
            }
            {
                const unsigned t = (unsigned)pk[k].z - pb;
                const unsigned a = t & (SEGB - 1);
                const float   ws = (t < (unsigned)SEGB) ? w4[k].z : 0.0f;
                a2 = fmaf(__half2float(*(const __half*)(xs + a)), ws, a2);
            }
            {
                const unsigned t = (unsigned)pk[k].w - pb;
                const unsigned a = t & (SEGB - 1);
                const float   ws = (t < (unsigned)SEGB) ? w4[k].w : 0.0f;
                a3 = fmaf(__half2float(*(const __half*)(xs + a)), ws, a3);
            }
        }

        if (p < NPASS - 1) {
            __syncthreads();             // probes of seg p done
            COMMIT();                    // write seg p+1 (vmcnt waited)
            if (p < NPASS - 2) ISSUE(p + 2);  // start loads for seg p+2
            __syncthreads();             // seg p+1 visible
        }
    }
#undef ISSUE
#undef COMMIT

    // Reduce across the 32 threads of my voxel (xor <= 16 stays within each
    // 32-lane half of the wave).
    float s = a0 + a1 + a2 + a3;
#pragma unroll
    for (int off = 16; off > 0; off >>= 1)
        s += __shfl_xor(s, off, 64);

    if (q == 0) {
        const int v = vox0 + vv;
        out[NVOX - 1 - v] = bias[v] + kScale * s;   // flip both spatial axes
    }
}

// ---------------------------------------------------------------------------
// Fallback (round-3 kernel, proven 305 us/dispatch) if workspace too small.
// ---------------------------------------------------------------------------
__global__ __launch_bounds__(256) void backproj_fallback_kernel(
    const float* __restrict__ x,
    const float* __restrict__ weight,
    const float* __restrict__ bias,
    const int*   __restrict__ indices,
    float*       __restrict__ out)
{
    const int wave_in_block = threadIdx.x >> 6;
    const int lane          = threadIdx.x & 63;
    const int v             = blockIdx.x * 4 + wave_in_block;
    const size_t base       = (size_t)v * PER_VOX;

    const v4i* ip = (const v4i*)(indices + base);
    const v4f* wp = (const v4f*)(weight + base);

    v4i i4[4];
#pragma unroll
    for (int k = 0; k < 4; ++k)
        i4[k] = __builtin_nontemporal_load(&ip[lane + k * 64]);

    float g[16];
#pragma unroll
    for (int k = 0; k < 4; ++k) {
        g[4 * k + 0] = x[i4[k].x];
        g[4 * k + 1] = x[i4[k].y];
        g[4 * k + 2] = x[i4[k].z];
        g[4 * k + 3] = x[i4[k].w];
    }

    v4f w4[4];
#pragma unroll
    for (int k = 0; k < 4; ++k)
        w4[k] = __builtin_nontemporal_load(&wp[lane + k * 64]);

    float s = 0.0f;
#pragma unroll
    for (int k = 0; k < 4; ++k) {
        s += g[4 * k + 0] * w4[k].x;
        s += g[4 * k + 1] * w4[k].y;
        s += g[4 * k + 2] * w4[k].z;
        s += g[4 * k + 3] * w4[k].w;
    }

#pragma unroll
    for (int off = 32; off > 0; off >>= 1)
        s += __shfl_down(s, off, 64);

    if (lane == 0)
        out[NVOX - 1 - v] = bias[v] + kScale * s;
}

extern "C" void kernel_launch(void* const* d_in, const int* in_sizes, int n_in,
                              void* d_out, int out_size, void* d_ws, size_t ws_size,
                              hipStream_t stream) {
    const float* x       = (const float*)d_in[0];
    const float* weight  = (const float*)d_in[1];
    const float* bias    = (const float*)d_in[2];
    const int*   indices = (const int*)d_in[3];
    float*       out     = (float*)d_out;

    if (ws_size >= (size_t)XWS_BYTES) {
        // Allow 128KB dynamic LDS (no-op if the runtime already permits it;
        // host-side attribute set, not a stream operation).
        static bool attr_done = false;
        if (!attr_done) {
            (void)hipFuncSetAttribute((const void*)backproj_lds2_kernel,
                                      hipFuncAttributeMaxDynamicSharedMemorySize,
                                      SEGB);
            attr_done = true;
        }
        ushort* xh = (ushort*)d_ws;
        convert_x_kernel<<<XWS_HALVES / 4 / 256, 256, 0, stream>>>(x, xh);
        backproj_lds2_kernel<<<NVOX / 32, 1024, SEGB, stream>>>(
            xh, weight, bias, indices, out);
    } else {
        backproj_fallback_kernel<<<NVOX / 4, 256, 0, stream>>>(
            x, weight, bias, indices, out);
    }
}